// Round 4
// baseline (1746.236 us; speedup 1.0000x reference)
//
#include <hip/hip_runtime.h>
#include <hip/hip_bf16.h>
#include <math.h>

#define N_NODES 100000
#define N_EDGES 3200000
#define IN_F 256
#define OUT_F 64
#define LRELU_SLOPE 0.2f

#define NB ((N_NODES + 63) >> 6)        // 1563 buckets of 64 nodes
#define NREP 8                          // replica counters per bucket
#define NC (NB * NREP)                  // 12504 counters
#define CPAD 8                          // counter padding: 8 ints = 32 B
#define SCAN_T 1024
#define SCAN_PER ((NC + SCAN_T - 1) / SCAN_T)   // 13

// ---------------------------------------------------------------------------
// K1: h = X @ W (bf16 store) fused with s_src = h@a[:64], s_dst = h@a[64:].
// 32 rows/block (4 waves x 8 rows), x-tile in LDS, W streamed from L1/L2.
// (unchanged from round 3 — not the bottleneck)
// ---------------------------------------------------------------------------
__global__ __launch_bounds__(256) void gemm_h_kernel(
    const float* __restrict__ in, const float* __restrict__ W,
    const float* __restrict__ a, __hip_bfloat16* __restrict__ h,
    float* __restrict__ s_src, float* __restrict__ s_dst) {
  __shared__ float xl[32 * IN_F];               // 32 KB
  const int w = threadIdx.x >> 6;
  const int col = threadIdx.x & 63;
  const int row0 = blockIdx.x * 32;

  const float4* gx = (const float4*)(in + (size_t)row0 * IN_F);
  float4* lx = (float4*)xl;
#pragma unroll
  for (int i = 0; i < 8; ++i)
    lx[i * 256 + threadIdx.x] = gx[i * 256 + threadIdx.x];
  __syncthreads();

  const float* xr = xl + (w * 8) * IN_F;
  float acc[8] = {0.f, 0.f, 0.f, 0.f, 0.f, 0.f, 0.f, 0.f};

  for (int k = 0; k < IN_F; k += 4) {
    float wv0 = W[(k + 0) * OUT_F + col];
    float wv1 = W[(k + 1) * OUT_F + col];
    float wv2 = W[(k + 2) * OUT_F + col];
    float wv3 = W[(k + 3) * OUT_F + col];
#pragma unroll
    for (int r = 0; r < 8; ++r) {
      float4 xv = *(const float4*)&xr[r * IN_F + k];
      acc[r] += xv.x * wv0 + xv.y * wv1 + xv.z * wv2 + xv.w * wv3;
    }
  }

  const float as = a[col];
  const float ad = a[OUT_F + col];
#pragma unroll
  for (int r = 0; r < 8; ++r) {
    const int row = row0 + w * 8 + r;
    h[(size_t)row * OUT_F + col] = __float2bfloat16(acc[r]);
    float vs = acc[r] * as;
    float vd = acc[r] * ad;
#pragma unroll
    for (int off = 32; off > 0; off >>= 1) {
      vs += __shfl_down(vs, off);
      vd += __shfl_down(vd, off);
    }
    if (col == 0) {
      s_src[row] = vs;
      s_dst[row] = vd;
    }
  }
}

// ---------------------------------------------------------------------------
// K2: bucket histogram with 8 replicas keyed by blockIdx&7 (must use the
// SAME grid shape + edge->thread mapping as the scatter kernel).
// Counters padded to 32B to avoid same-line cross-XCD atomic chains.
// ---------------------------------------------------------------------------
__global__ __launch_bounds__(256) void bucket_hist_kernel(
    const int* __restrict__ src, int* __restrict__ bcount) {
  const int e = blockIdx.x * 256 + threadIdx.x;
  if (e >= N_EDGES) return;
  const int b = src[e] >> 6;
  const int c = (b << 3) | (blockIdx.x & 7);
  atomicAdd(&bcount[c * CPAD], 1);
}

// ---------------------------------------------------------------------------
// K3: single-block exclusive scan over the 12504 (bucket,replica) counts.
// Writes padded scursor (scatter cursors) and compact bstart[NB+1]
// (bucket ranges for the aggregate kernel).
// ---------------------------------------------------------------------------
__global__ __launch_bounds__(SCAN_T) void bucket_scan_kernel(
    const int* __restrict__ bcount, int* __restrict__ scursor,
    int* __restrict__ bstart) {
  __shared__ int ts[SCAN_T];
  const int t = threadIdx.x;
  const int base = t * SCAN_PER;

  int local[SCAN_PER];
  int sum = 0;
#pragma unroll
  for (int k = 0; k < SCAN_PER; ++k) {
    const int c = base + k;
    const int v = (c < NC) ? bcount[c * CPAD] : 0;
    local[k] = sum;                       // exclusive within thread
    sum += v;
  }
  ts[t] = sum;
  __syncthreads();
  for (int off = 1; off < SCAN_T; off <<= 1) {
    int tv = (t >= off) ? ts[t - off] : 0;
    __syncthreads();
    ts[t] += tv;
    __syncthreads();
  }
  const int texcl = (t > 0) ? ts[t - 1] : 0;
#pragma unroll
  for (int k = 0; k < SCAN_PER; ++k) {
    const int c = base + k;
    if (c < NC) {
      const int excl = texcl + local[k];
      scursor[c * CPAD] = excl;
      if ((c & (NREP - 1)) == 0) bstart[c >> 3] = excl;
    }
  }
  if (t == 0) bstart[NB] = N_EDGES;
}

// ---------------------------------------------------------------------------
// K4: bucket-major partition. Write frontier = ~1563 lines (L2-resident),
// so staged lines fill completely -> ~12.8 MB HBM write instead of the
// round-3 194 MB line-thrash. Payload packs (src&63)<<17 | dst in 4B.
// ---------------------------------------------------------------------------
__global__ __launch_bounds__(256) void bucket_scatter_kernel(
    const int* __restrict__ src, const int* __restrict__ dst,
    int* __restrict__ scursor, unsigned int* __restrict__ staged) {
  const int e = blockIdx.x * 256 + threadIdx.x;
  if (e >= N_EDGES) return;
  const int s = src[e];
  const int d = dst[e];
  const int b = s >> 6;
  const int c = (b << 3) | (blockIdx.x & 7);
  const int p = atomicAdd(&scursor[c * CPAD], 1);
  staged[p] = ((unsigned int)(s & 63) << 17) | (unsigned int)d;
}

// ---------------------------------------------------------------------------
// K5: one block per bucket. 64x64 fp32 accumulator + rowsum in LDS
// (native ds_add_f32 atomics; acc[ls*64+lane] is 2-way bank aliasing =
// free). ee recomputed from s_src/s_dst. Fused ELU epilogue writes d_out.
// Wave-per-edge, lane = feature, EPW=4 batched for memory-level parallelism.
// ---------------------------------------------------------------------------
#define EPW 4
__global__ __launch_bounds__(256) void bucket_aggregate_kernel(
    const int* __restrict__ bstart, const unsigned int* __restrict__ staged,
    const float* __restrict__ s_src, const float* __restrict__ s_dst,
    const __hip_bfloat16* __restrict__ h, float* __restrict__ out) {
  __shared__ float acc[64 * 64];
  __shared__ float rs[64];
  const int b = blockIdx.x;
  const int lane = threadIdx.x & 63;
  const int wv = threadIdx.x >> 6;
  const int node0 = b << 6;

  for (int i = threadIdx.x; i < 64 * 64; i += 256) acc[i] = 0.f;
  if (threadIdx.x < 64) rs[threadIdx.x] = 0.f;
  __syncthreads();

  const int e0 = bstart[b];
  const int e1 = bstart[b + 1];

  for (int e = e0 + wv * EPW; e < e1; e += 4 * EPW) {
    const int n = min(EPW, e1 - e);
    unsigned int pk[EPW];
    float hv[EPW];
    int ls[EPW], d[EPW];
#pragma unroll
    for (int j = 0; j < EPW; ++j)
      pk[j] = (j < n) ? staged[e + j] : 0u;
#pragma unroll
    for (int j = 0; j < EPW; ++j) {
      ls[j] = (int)(pk[j] >> 17);
      d[j] = (int)(pk[j] & 0x1FFFFu);
    }
#pragma unroll
    for (int j = 0; j < EPW; ++j)
      if (j < n) hv[j] = __bfloat162float(h[(size_t)d[j] * OUT_F + lane]);
#pragma unroll
    for (int j = 0; j < EPW; ++j) {
      if (j < n) {
        const float sc = s_src[node0 + ls[j]] + s_dst[d[j]];
        const float lr = sc > 0.f ? sc : LRELU_SLOPE * sc;
        const float ev = expf(-lr);
        atomicAdd(&acc[ls[j] * 64 + lane], ev * hv[j]);
        if (lane == 0) atomicAdd(&rs[ls[j]], ev);
      }
    }
  }
  __syncthreads();

  // epilogue: out = elu(acc / rowsum) for this bucket's 64 nodes
  for (int i = threadIdx.x; i < 64 * 64; i += 256) {
    const int node = node0 + (i >> 6);
    if (node < N_NODES) {
      const float v = acc[i] / rs[i >> 6];
      out[(size_t)node0 * 64 + i] = v > 0.f ? v : expm1f(v);
    }
  }
}

extern "C" void kernel_launch(void* const* d_in, const int* in_sizes, int n_in,
                              void* d_out, int out_size, void* d_ws, size_t ws_size,
                              hipStream_t stream) {
  const float* in = (const float*)d_in[0];
  const int* edge = (const int*)d_in[1];
  const float* W = (const float*)d_in[2];
  const float* a = (const float*)d_in[3];
  float* out = (float*)d_out;

  const int* src = edge;
  const int* dst = edge + N_EDGES;

  // workspace: 12.8 + 0.8 + 12.8 + 0.4 + 0.4 + ~0.006 MB = 27.2 MB
  // (round 3 proved ws_size >= 27.66 MB)
  char* p = (char*)d_ws;
  __hip_bfloat16* h = (__hip_bfloat16*)p; p += (size_t)N_NODES * OUT_F * 2;
  float* s_src = (float*)p;               p += (size_t)N_NODES * 4;
  float* s_dst = (float*)p;               p += (size_t)N_NODES * 4;
  unsigned int* staged = (unsigned int*)p; p += (size_t)N_EDGES * 4;
  int* bcount = (int*)p;                  p += (size_t)NC * CPAD * 4;
  int* scursor = (int*)p;                 p += (size_t)NC * CPAD * 4;
  int* bstart = (int*)p;                  p += (size_t)(NB + 1) * 4;

  hipMemsetAsync(bcount, 0, (size_t)NC * CPAD * 4, stream);

  gemm_h_kernel<<<N_NODES / 32, 256, 0, stream>>>(in, W, a, h, s_src, s_dst);
  bucket_hist_kernel<<<(N_EDGES + 255) / 256, 256, 0, stream>>>(src, bcount);
  bucket_scan_kernel<<<1, SCAN_T, 0, stream>>>(bcount, scursor, bstart);
  bucket_scatter_kernel<<<(N_EDGES + 255) / 256, 256, 0, stream>>>(
      src, dst, scursor, staged);
  bucket_aggregate_kernel<<<NB, 256, 0, stream>>>(bstart, staged, s_src,
                                                  s_dst, h, out);
}

// Round 5
// 686.547 us; speedup vs baseline: 2.5435x; 2.5435x over previous
//
#include <hip/hip_runtime.h>
#include <hip/hip_bf16.h>
#include <math.h>

#define N_NODES 100000
#define N_EDGES 3200000
#define IN_F 256
#define OUT_F 64
#define LRELU_SLOPE 0.2f

#define NB 1563                         // buckets of 64 src nodes
#define NREP 8                          // replica counters (keyed blockIdx&7)
#define NC (NB * NREP)                  // 12504
#define SCAN_T 1024
#define SCAN_PER ((NC + SCAN_T - 1) / SCAN_T)   // 13
#define CAP 3072                        // per-chunk LDS edge capacity (22 sigma)

// ---------------------------------------------------------------------------
// K1: h = X @ W (bf16 store) fused with s_src = h@a[:64], s_dst = h@a[64:].
// ---------------------------------------------------------------------------
__global__ __launch_bounds__(256) void gemm_h_kernel(
    const float* __restrict__ in, const float* __restrict__ W,
    const float* __restrict__ a, __hip_bfloat16* __restrict__ h,
    float* __restrict__ s_src, float* __restrict__ s_dst) {
  __shared__ float xl[32 * IN_F];               // 32 KB
  const int w = threadIdx.x >> 6;
  const int col = threadIdx.x & 63;
  const int row0 = blockIdx.x * 32;

  const float4* gx = (const float4*)(in + (size_t)row0 * IN_F);
  float4* lx = (float4*)xl;
#pragma unroll
  for (int i = 0; i < 8; ++i)
    lx[i * 256 + threadIdx.x] = gx[i * 256 + threadIdx.x];
  __syncthreads();

  const float* xr = xl + (w * 8) * IN_F;
  float acc[8] = {0.f, 0.f, 0.f, 0.f, 0.f, 0.f, 0.f, 0.f};

  for (int k = 0; k < IN_F; k += 4) {
    float wv0 = W[(k + 0) * OUT_F + col];
    float wv1 = W[(k + 1) * OUT_F + col];
    float wv2 = W[(k + 2) * OUT_F + col];
    float wv3 = W[(k + 3) * OUT_F + col];
#pragma unroll
    for (int r = 0; r < 8; ++r) {
      float4 xv = *(const float4*)&xr[r * IN_F + k];
      acc[r] += xv.x * wv0 + xv.y * wv1 + xv.z * wv2 + xv.w * wv3;
    }
  }

  const float as = a[col];
  const float ad = a[OUT_F + col];
#pragma unroll
  for (int r = 0; r < 8; ++r) {
    const int row = row0 + w * 8 + r;
    h[(size_t)row * OUT_F + col] = __float2bfloat16(acc[r]);
    float vs = acc[r] * as;
    float vd = acc[r] * ad;
#pragma unroll
    for (int off = 32; off > 0; off >>= 1) {
      vs += __shfl_down(vs, off);
      vd += __shfl_down(vd, off);
    }
    if (col == 0) {
      s_src[row] = vs;
      s_dst[row] = vd;
    }
  }
}

// ---------------------------------------------------------------------------
// K2: bucket histogram. Counter slot = (blockIdx&7)*NB + (src>>6):
// replica-major so each XCD's atomics stay in its own 6.25 KB region.
// Grid is exactly N_EDGES/256 blocks; mapping must match K4.
// ---------------------------------------------------------------------------
__global__ __launch_bounds__(256) void bucket_hist_kernel(
    const int* __restrict__ src, int* __restrict__ bctr) {
  const int e = blockIdx.x * 256 + threadIdx.x;
  const int b = src[e] >> 6;
  atomicAdd(&bctr[(blockIdx.x & 7) * NB + b], 1);
}

// ---------------------------------------------------------------------------
// K3: single-block exclusive scan over ordinals o = bucket*8 + replica
// (storage slot (o&7)*NB + (o>>3)), in place: bctr becomes scatter cursors.
// Also emits bstart[NB+1] = per-bucket edge ranges (contiguous by design).
// ---------------------------------------------------------------------------
__global__ __launch_bounds__(SCAN_T) void bucket_scan_kernel(
    int* __restrict__ bctr, int* __restrict__ bstart) {
  __shared__ int ts[SCAN_T];
  const int t = threadIdx.x;
  int local[SCAN_PER];
  int sum = 0;
#pragma unroll
  for (int k = 0; k < SCAN_PER; ++k) {
    const int o = t * SCAN_PER + k;
    int v = 0;
    if (o < NC) v = bctr[(o & 7) * NB + (o >> 3)];
    local[k] = sum;
    sum += v;
  }
  ts[t] = sum;
  __syncthreads();
  for (int off = 1; off < SCAN_T; off <<= 1) {
    int tv = (t >= off) ? ts[t - off] : 0;
    __syncthreads();
    ts[t] += tv;
    __syncthreads();
  }
  const int texcl = (t > 0) ? ts[t - 1] : 0;
#pragma unroll
  for (int k = 0; k < SCAN_PER; ++k) {
    const int o = t * SCAN_PER + k;
    if (o < NC) {
      const int excl = texcl + local[k];
      bctr[(o & 7) * NB + (o >> 3)] = excl;   // same slot this thread read
      if ((o & 7) == 0) bstart[o >> 3] = excl;
    }
  }
  if (t == 0) bstart[NB] = N_EDGES;
}

// ---------------------------------------------------------------------------
// K4: bucket-major partition. Write frontier ~100 KB/XCD (L2-resident) ->
// staged lines fill before eviction. Packs (src&63)<<17 | dst in 4 B.
// ---------------------------------------------------------------------------
__global__ __launch_bounds__(256) void bucket_scatter_kernel(
    const int* __restrict__ src, const int* __restrict__ dst,
    int* __restrict__ bctr, unsigned int* __restrict__ staged) {
  const int e = blockIdx.x * 256 + threadIdx.x;
  const int s = src[e];
  const int d = dst[e];
  const int p = atomicAdd(&bctr[(blockIdx.x & 7) * NB + (s >> 6)], 1);
  staged[p] = ((unsigned int)(s & 63) << 17) | (unsigned int)d;
}

// ---------------------------------------------------------------------------
// K5: one block per bucket. Counting-sort the bucket's edges by local src
// into LDS (ee computed ONCE per edge, __expf), then each wave owns 16
// nodes and accumulates in REGISTERS (no LDS atomics in the hot loop).
// 4-edge batched gathers for MLP. Fused ELU epilogue. Chunked at CAP for
// distribution-independence (1 chunk in practice).
// ---------------------------------------------------------------------------
__global__ __launch_bounds__(256) void sort_aggregate_kernel(
    const int* __restrict__ bstart, const unsigned int* __restrict__ staged,
    const float* __restrict__ s_src, const float* __restrict__ s_dst,
    const __hip_bfloat16* __restrict__ h, float* __restrict__ out) {
  __shared__ unsigned int eds_d[CAP];   // 12 KB
  __shared__ float eds_e[CAP];          // 12 KB
  __shared__ float ssrc[64];
  __shared__ int lcnt[64];
  __shared__ int lstart[65];
  __shared__ int lcur[64];

  const int b = blockIdx.x;
  const int tid = threadIdx.x;
  const int lane = tid & 63;
  const int wv = tid >> 6;
  const int node0 = b << 6;

  if (tid < 64)
    ssrc[tid] = (node0 + tid < N_NODES) ? s_src[node0 + tid] : 0.f;

  const int e0 = bstart[b];
  const int e1 = bstart[b + 1];

  float acc[16], rsn[16];
#pragma unroll
  for (int j = 0; j < 16; ++j) { acc[j] = 0.f; rsn[j] = 0.f; }

  for (int c0 = e0; c0 < e1; c0 += CAP) {
    const int cc = min(CAP, e1 - c0);
    __syncthreads();                    // protect eds/lcnt reuse across chunks
    if (tid < 64) lcnt[tid] = 0;
    __syncthreads();

    // phase A: histogram of local src
    for (int i = tid; i < cc; i += 256)
      atomicAdd(&lcnt[staged[c0 + i] >> 17], 1);
    __syncthreads();

    // scan of 64 counters in wave 0
    if (tid < 64) {
      int v = lcnt[tid];
#pragma unroll
      for (int off = 1; off < 64; off <<= 1) {
        int tv = __shfl_up(v, off);
        if (lane >= off) v += tv;
      }
      lstart[tid + 1] = v;
      if (tid == 0) lstart[0] = 0;
      lcur[tid] = v - lcnt[tid];
    }
    __syncthreads();

    // phase B: compute ee once per edge, scatter sorted into LDS
    for (int i = tid; i < cc; i += 256) {
      const unsigned int pk = staged[c0 + i];
      const int ls = (int)(pk >> 17);
      const int d = (int)(pk & 0x1FFFFu);
      const float sc = ssrc[ls] + s_dst[d];
      const float lr = sc > 0.f ? sc : LRELU_SLOPE * sc;
      const float ev = __expf(-lr);
      const int p = atomicAdd(&lcur[ls], 1);
      eds_d[p] = (unsigned int)d;
      eds_e[p] = ev;
    }
    __syncthreads();

    // phase C: wave wv accumulates its 16 nodes in registers
#pragma unroll
    for (int j = 0; j < 16; ++j) {
      const int n = wv + 4 * j;
      const int iend = lstart[n + 1];
      int i = lstart[n];
      float p0 = 0.f, p1 = 0.f, rv = 0.f;
      for (; i + 4 <= iend; i += 4) {
        const int d0 = eds_d[i + 0], d1 = eds_d[i + 1];
        const int d2 = eds_d[i + 2], d3 = eds_d[i + 3];
        const float v0 = eds_e[i + 0], v1 = eds_e[i + 1];
        const float v2 = eds_e[i + 2], v3 = eds_e[i + 3];
        const float h0 = __bfloat162float(h[(size_t)d0 * OUT_F + lane]);
        const float h1 = __bfloat162float(h[(size_t)d1 * OUT_F + lane]);
        const float h2 = __bfloat162float(h[(size_t)d2 * OUT_F + lane]);
        const float h3 = __bfloat162float(h[(size_t)d3 * OUT_F + lane]);
        p0 += v0 * h0 + v2 * h2;
        p1 += v1 * h1 + v3 * h3;
        rv += (v0 + v1) + (v2 + v3);
      }
      for (; i < iend; ++i) {
        const int d0 = eds_d[i];
        const float v0 = eds_e[i];
        p0 += v0 * __bfloat162float(h[(size_t)d0 * OUT_F + lane]);
        rv += v0;
      }
      acc[j] += p0 + p1;
      rsn[j] += rv;
    }
  }

  // epilogue: out = elu(acc / rowsum)
#pragma unroll
  for (int j = 0; j < 16; ++j) {
    const int node = node0 + wv + 4 * j;
    if (node < N_NODES) {
      const float v = acc[j] / rsn[j];
      out[(size_t)node * OUT_F + lane] = v > 0.f ? v : expm1f(v);
    }
  }
}

extern "C" void kernel_launch(void* const* d_in, const int* in_sizes, int n_in,
                              void* d_out, int out_size, void* d_ws, size_t ws_size,
                              hipStream_t stream) {
  const float* in = (const float*)d_in[0];
  const int* edge = (const int*)d_in[1];
  const float* W = (const float*)d_in[2];
  const float* a = (const float*)d_in[3];
  float* out = (float*)d_out;

  const int* src = edge;
  const int* dst = edge + N_EDGES;

  // workspace: 12.8 + 0.4 + 0.4 + 12.8 + 0.05 + 0.006 MB = 26.5 MB
  char* p = (char*)d_ws;
  __hip_bfloat16* h = (__hip_bfloat16*)p;  p += (size_t)N_NODES * OUT_F * 2;
  float* s_src = (float*)p;                p += (size_t)N_NODES * 4;
  float* s_dst = (float*)p;                p += (size_t)N_NODES * 4;
  unsigned int* staged = (unsigned int*)p; p += (size_t)N_EDGES * 4;
  int* bctr = (int*)p;                     p += (size_t)NC * 4;
  int* bstart = (int*)p;                   p += (size_t)(NB + 1) * 4;

  hipMemsetAsync(bctr, 0, (size_t)NC * 4, stream);

  gemm_h_kernel<<<N_NODES / 32, 256, 0, stream>>>(in, W, a, h, s_src, s_dst);
  bucket_hist_kernel<<<N_EDGES / 256, 256, 0, stream>>>(src, bctr);
  bucket_scan_kernel<<<1, SCAN_T, 0, stream>>>(bctr, bstart);
  bucket_scatter_kernel<<<N_EDGES / 256, 256, 0, stream>>>(src, dst, bctr,
                                                           staged);
  sort_aggregate_kernel<<<NB, 256, 0, stream>>>(bstart, staged, s_src, s_dst,
                                                h, out);
}

// Round 6
// 681.136 us; speedup vs baseline: 2.5637x; 1.0079x over previous
//
#include <hip/hip_runtime.h>
#include <hip/hip_bf16.h>
#include <math.h>

#define N_NODES 100000
#define N_EDGES 3200000
#define IN_F 256
#define OUT_F 64
#define LRELU_SLOPE 0.2f

#define NB 1563                         // buckets of 64 src nodes
#define NREP 32                         // replica counters (keyed blockIdx&31)
#define NC (NB * NREP)                  // 50016
#define SCAN_T 1024
#define SCAN_PER ((NC + SCAN_T - 1) / SCAN_T)   // 49
#define CAP 3072                        // per-chunk LDS edge capacity
#define XPITCH 264                      // LDS row pitch in bf16 (2-way banks)

typedef __attribute__((ext_vector_type(8))) short bf16x8;
typedef __attribute__((ext_vector_type(4))) float f32x4;

// ---------------------------------------------------------------------------
// K0: W (256x64 fp32) -> wt (64x256 bf16, transposed). 64 blocks x 256 thr.
// ---------------------------------------------------------------------------
__global__ __launch_bounds__(256) void wt_kernel(
    const float* __restrict__ W, __hip_bfloat16* __restrict__ wt) {
  wt[blockIdx.x * 256 + threadIdx.x] =
      __float2bfloat16(W[threadIdx.x * 64 + blockIdx.x]);
}

// ---------------------------------------------------------------------------
// K1: h = X @ W via bf16 MFMA 16x16x32, fused s_src = h@a[:64],
// s_dst = h@a[64:]. 64 rows/block, 4 waves; wave w owns rows [16w,16w+16).
// X staged fp32->bf16 in LDS (pitch 264: frag reads ~2-way = free);
// B-frags read 16B from pre-transposed wt (L1-resident, 32 KB).
// A: m=lane&15, k=quad*8+j (m120); C/D: col=lane&15, row=quad*4+reg (m89).
// ---------------------------------------------------------------------------
__global__ __launch_bounds__(256) void gemm_h_kernel(
    const float* __restrict__ in, const __hip_bfloat16* __restrict__ wt,
    const float* __restrict__ a, __hip_bfloat16* __restrict__ h,
    float* __restrict__ s_src, float* __restrict__ s_dst) {
  __shared__ __hip_bfloat16 xl[64 * XPITCH];    // 33792 B
  const int tid = threadIdx.x;
  const int r0 = blockIdx.x * 64;

  // stage X: 64 rows x 256 k, fp32 -> bf16, b64 chunks of 4 k
#pragma unroll
  for (int i = 0; i < 16; ++i) {
    const int e = i * 256 + tid;        // e in [0,4096)
    const int row = e >> 6, kc = e & 63;
    const int grow = r0 + row;
    float4 v = make_float4(0.f, 0.f, 0.f, 0.f);
    if (grow < N_NODES)
      v = *(const float4*)&in[(size_t)grow * IN_F + kc * 4];
    __hip_bfloat16 b4[4] = {__float2bfloat16(v.x), __float2bfloat16(v.y),
                            __float2bfloat16(v.z), __float2bfloat16(v.w)};
    *(uint2*)&xl[row * XPITCH + kc * 4] = *(uint2*)b4;
  }
  __syncthreads();

  const int w = tid >> 6, lane = tid & 63;
  const int lm = lane & 15, lg = lane >> 4;

  f32x4 acc[4];
#pragma unroll
  for (int ct = 0; ct < 4; ++ct) acc[ct] = (f32x4){0.f, 0.f, 0.f, 0.f};

  const __hip_bfloat16* xbase = &xl[(w * 16 + lm) * XPITCH + lg * 8];
  const __hip_bfloat16* wbase = &wt[(size_t)lm * IN_F + lg * 8];

#pragma unroll
  for (int kt = 0; kt < 8; ++kt) {
    bf16x8 af = *(const bf16x8*)(xbase + kt * 32);
#pragma unroll
    for (int ct = 0; ct < 4; ++ct) {
      bf16x8 bfr = *(const bf16x8*)(wbase + (size_t)ct * 16 * IN_F + kt * 32);
      acc[ct] = __builtin_amdgcn_mfma_f32_16x16x32_bf16(af, bfr, acc[ct],
                                                        0, 0, 0);
    }
  }

  // epilogue: h store (bf16) + per-row s reductions over the 16-lane quad grp
  float as[4], ad[4];
#pragma unroll
  for (int ct = 0; ct < 4; ++ct) {
    as[ct] = a[ct * 16 + lm];
    ad[ct] = a[OUT_F + ct * 16 + lm];
  }
#pragma unroll
  for (int reg = 0; reg < 4; ++reg) {
    const int row = r0 + w * 16 + lg * 4 + reg;
    float vs = 0.f, vd = 0.f;
    if (row < N_NODES) {
#pragma unroll
      for (int ct = 0; ct < 4; ++ct) {
        const float v = acc[ct][reg];
        h[(size_t)row * OUT_F + ct * 16 + lm] = __float2bfloat16(v);
        vs += v * as[ct];
        vd += v * ad[ct];
      }
    }
#pragma unroll
    for (int m = 1; m < 16; m <<= 1) {    // reduce within quad group
      vs += __shfl_xor(vs, m);
      vd += __shfl_xor(vd, m);
    }
    if (lm == 0 && row < N_NODES) {
      s_src[row] = vs;
      s_dst[row] = vd;
    }
  }
}

// ---------------------------------------------------------------------------
// K2: bucket histogram, int4 reads (4 edges/thread), 32 replicas
// replica-major: slot = (blockIdx&31)*NB + bucket. Grid must match K4.
// ---------------------------------------------------------------------------
__global__ __launch_bounds__(256) void bucket_hist_kernel(
    const int4* __restrict__ src4, int* __restrict__ bctr) {
  const int t = blockIdx.x * 256 + threadIdx.x;
  const int4 s = src4[t];
  int* r = bctr + (blockIdx.x & 31) * NB;
  atomicAdd(&r[s.x >> 6], 1);
  atomicAdd(&r[s.y >> 6], 1);
  atomicAdd(&r[s.z >> 6], 1);
  atomicAdd(&r[s.w >> 6], 1);
}

// ---------------------------------------------------------------------------
// K3: single-block exclusive scan over ordinals o = bucket*32 + replica
// (slot (o&31)*NB + (o>>5)), in place -> scatter cursors + bstart[NB+1].
// ---------------------------------------------------------------------------
__global__ __launch_bounds__(SCAN_T) void bucket_scan_kernel(
    int* __restrict__ bctr, int* __restrict__ bstart) {
  __shared__ int ts[SCAN_T];
  const int t = threadIdx.x;
  int local[SCAN_PER];
  int sum = 0;
#pragma unroll
  for (int k = 0; k < SCAN_PER; ++k) {
    const int o = t * SCAN_PER + k;
    int v = 0;
    if (o < NC) v = bctr[(o & 31) * NB + (o >> 5)];
    local[k] = sum;
    sum += v;
  }
  ts[t] = sum;
  __syncthreads();
  for (int off = 1; off < SCAN_T; off <<= 1) {
    int tv = (t >= off) ? ts[t - off] : 0;
    __syncthreads();
    ts[t] += tv;
    __syncthreads();
  }
  const int texcl = (t > 0) ? ts[t - 1] : 0;
#pragma unroll
  for (int k = 0; k < SCAN_PER; ++k) {
    const int o = t * SCAN_PER + k;
    if (o < NC) {
      const int excl = texcl + local[k];
      bctr[(o & 31) * NB + (o >> 5)] = excl;
      if ((o & 31) == 0) bstart[o >> 5] = excl;
    }
  }
  if (t == 0) bstart[NB] = N_EDGES;
}

// ---------------------------------------------------------------------------
// K4: bucket-major partition, int4 reads, replica = blockIdx&31 (same
// mapping as K2 -> sub-segment sizes match counts by construction).
// ---------------------------------------------------------------------------
__global__ __launch_bounds__(256) void bucket_scatter_kernel(
    const int4* __restrict__ src4, const int4* __restrict__ dst4,
    int* __restrict__ bctr, unsigned int* __restrict__ staged) {
  const int t = blockIdx.x * 256 + threadIdx.x;
  const int4 s = src4[t];
  const int4 d = dst4[t];
  int* r = bctr + (blockIdx.x & 31) * NB;
  int p;
  p = atomicAdd(&r[s.x >> 6], 1);
  staged[p] = ((unsigned)(s.x & 63) << 17) | (unsigned)d.x;
  p = atomicAdd(&r[s.y >> 6], 1);
  staged[p] = ((unsigned)(s.y & 63) << 17) | (unsigned)d.y;
  p = atomicAdd(&r[s.z >> 6], 1);
  staged[p] = ((unsigned)(s.z & 63) << 17) | (unsigned)d.z;
  p = atomicAdd(&r[s.w >> 6], 1);
  staged[p] = ((unsigned)(s.w & 63) << 17) | (unsigned)d.w;
}

// ---------------------------------------------------------------------------
// K5: one block per bucket. LDS counting sort by local src (ee computed
// once per edge), then register accumulate: wave owns 16 nodes, 4-edge
// batched bf16 gathers. eds packed as uint2 {dst, ee} -> single b64 op.
// ---------------------------------------------------------------------------
__global__ __launch_bounds__(256) void sort_aggregate_kernel(
    const int* __restrict__ bstart, const unsigned int* __restrict__ staged,
    const float* __restrict__ s_src, const float* __restrict__ s_dst,
    const __hip_bfloat16* __restrict__ h, float* __restrict__ out) {
  __shared__ uint2 eds[CAP];            // 24 KB
  __shared__ float ssrc[64];
  __shared__ int lcnt[64];
  __shared__ int lstart[65];
  __shared__ int lcur[64];

  const int b = blockIdx.x;
  const int tid = threadIdx.x;
  const int lane = tid & 63;
  const int wv = tid >> 6;
  const int node0 = b << 6;

  if (tid < 64)
    ssrc[tid] = (node0 + tid < N_NODES) ? s_src[node0 + tid] : 0.f;

  const int e0 = bstart[b];
  const int e1 = bstart[b + 1];

  float acc[16], rsn[16];
#pragma unroll
  for (int j = 0; j < 16; ++j) { acc[j] = 0.f; rsn[j] = 0.f; }

  for (int c0 = e0; c0 < e1; c0 += CAP) {
    const int cc = min(CAP, e1 - c0);
    __syncthreads();
    if (tid < 64) lcnt[tid] = 0;
    __syncthreads();

    // phase A: histogram of local src
    for (int i = tid; i < cc; i += 256)
      atomicAdd(&lcnt[staged[c0 + i] >> 17], 1);
    __syncthreads();

    // wave-0 scan of the 64 counters
    if (tid < 64) {
      int v = lcnt[tid];
#pragma unroll
      for (int off = 1; off < 64; off <<= 1) {
        int tv = __shfl_up(v, off);
        if (lane >= off) v += tv;
      }
      lstart[tid + 1] = v;
      if (tid == 0) lstart[0] = 0;
      lcur[tid] = v - lcnt[tid];
    }
    __syncthreads();

    // phase B: ee once per edge, scatter sorted into LDS (packed b64)
    for (int i = tid; i < cc; i += 256) {
      const unsigned pk = staged[c0 + i];
      const int ls = (int)(pk >> 17);
      const int d = (int)(pk & 0x1FFFFu);
      const float sc = ssrc[ls] + s_dst[d];
      const float lr = sc > 0.f ? sc : LRELU_SLOPE * sc;
      const float ev = __expf(-lr);
      const int p = atomicAdd(&lcur[ls], 1);
      eds[p] = make_uint2((unsigned)d, __float_as_uint(ev));
    }
    __syncthreads();

    // phase C: wave wv accumulates its 16 nodes in registers
#pragma unroll
    for (int j = 0; j < 16; ++j) {
      const int n = wv + 4 * j;
      const int iend = lstart[n + 1];
      int i = lstart[n];
      float p0 = 0.f, p1 = 0.f, rv = 0.f;
      for (; i + 4 <= iend; i += 4) {
        const uint2 q0 = eds[i + 0], q1 = eds[i + 1];
        const uint2 q2 = eds[i + 2], q3 = eds[i + 3];
        const float v0 = __uint_as_float(q0.y), v1 = __uint_as_float(q1.y);
        const float v2 = __uint_as_float(q2.y), v3 = __uint_as_float(q3.y);
        const float h0 = __bfloat162float(h[(size_t)q0.x * OUT_F + lane]);
        const float h1 = __bfloat162float(h[(size_t)q1.x * OUT_F + lane]);
        const float h2 = __bfloat162float(h[(size_t)q2.x * OUT_F + lane]);
        const float h3 = __bfloat162float(h[(size_t)q3.x * OUT_F + lane]);
        p0 += v0 * h0 + v2 * h2;
        p1 += v1 * h1 + v3 * h3;
        rv += (v0 + v1) + (v2 + v3);
      }
      for (; i < iend; ++i) {
        const uint2 q0 = eds[i];
        const float v0 = __uint_as_float(q0.y);
        p0 += v0 * __bfloat162float(h[(size_t)q0.x * OUT_F + lane]);
        rv += v0;
      }
      acc[j] += p0 + p1;
      rsn[j] += rv;
    }
  }

  // epilogue: out = elu(acc / rowsum)
#pragma unroll
  for (int j = 0; j < 16; ++j) {
    const int node = node0 + wv + 4 * j;
    if (node < N_NODES) {
      const float v = acc[j] / rsn[j];
      out[(size_t)node * OUT_F + lane] = v > 0.f ? v : expm1f(v);
    }
  }
}

extern "C" void kernel_launch(void* const* d_in, const int* in_sizes, int n_in,
                              void* d_out, int out_size, void* d_ws, size_t ws_size,
                              hipStream_t stream) {
  const float* in = (const float*)d_in[0];
  const int* edge = (const int*)d_in[1];
  const float* W = (const float*)d_in[2];
  const float* a = (const float*)d_in[3];
  float* out = (float*)d_out;

  const int4* src4 = (const int4*)edge;
  const int4* dst4 = (const int4*)(edge + N_EDGES);

  // workspace: 12.8 + 0.4 + 0.4 + 12.8 + 0.2 + 0.006 + 0.03 MB = 26.7 MB
  char* p = (char*)d_ws;
  __hip_bfloat16* h = (__hip_bfloat16*)p;  p += (size_t)N_NODES * OUT_F * 2;
  float* s_src = (float*)p;                p += (size_t)N_NODES * 4;
  float* s_dst = (float*)p;                p += (size_t)N_NODES * 4;
  unsigned int* staged = (unsigned int*)p; p += (size_t)N_EDGES * 4;
  int* bctr = (int*)p;                     p += (size_t)NC * 4;
  int* bstart = (int*)p;                   p += (size_t)(NB + 1) * 4 + 12;
  __hip_bfloat16* wt = (__hip_bfloat16*)p; p += (size_t)OUT_F * IN_F * 2;

  hipMemsetAsync(bctr, 0, (size_t)NC * 4, stream);

  wt_kernel<<<OUT_F, 256, 0, stream>>>(W, wt);
  gemm_h_kernel<<<(N_NODES + 63) / 64, 256, 0, stream>>>(in, wt, a, h, s_src,
                                                         s_dst);
  bucket_hist_kernel<<<N_EDGES / 1024, 256, 0, stream>>>(src4, bctr);
  bucket_scan_kernel<<<1, SCAN_T, 0, stream>>>(bctr, bstart);
  bucket_scatter_kernel<<<N_EDGES / 1024, 256, 0, stream>>>(src4, dst4, bctr,
                                                            staged);
  sort_aggregate_kernel<<<NB, 256, 0, stream>>>(bstart, staged, s_src, s_dst,
                                                h, out);
}